// Round 6
// baseline (259.078 us; speedup 1.0000x reference)
//
#include <hip/hip_runtime.h>
#include <hip/hip_bf16.h>

// ConvNeXtLoss: fused attention-BCE + dice + reverse-dice over (16,4,512,512).
// Single kernel: per-(b,c)-plane partial sums + last-block finalize.
//
// R6 changes vs R5 (258 us DISASTER: inline-asm loads + "memory"-clobber
// waitcnt asm made SIInsertWaitcnts drain vmcnt(0) around each step ->
// pipeline depth 0, VGPR=36, VALUBusy 2.4%):
//  - NO inline asm. Plain vector loads for all 8 pairs, then ONE
//    __builtin_amdgcn_sched_barrier(0) pins them above the compute
//    (R3's failure was the machine scheduler sinking them; barrier splits
//    the scheduling region). Compiler's own waitcnt pass then emits exact
//    counted vmcnt(14),(12),... before each pair's first use.
//  - __launch_bounds__(256,4): 128-VGPR budget, ~64 data VGPRs live, no
//    spill, 16 waves/CU.
//  - finalize fused via last-block pattern (R5-validated: memset counter
//    to 0 each call, trigger old==NBLOCKS-1).

typedef float f32x4 __attribute__((ext_vector_type(4)));
typedef int   i32x4 __attribute__((ext_vector_type(4)));

#define B_DIM 16
#define C_DIM 4
#define HW 262144            // 512*512 plane
#define NPLANES 64           // B*C
#define K_CHUNKS 32          // blocks per plane
#define CHUNK (HW / K_CHUNKS)  // 8192 elements per block
#define NBLOCKS (NPLANES * K_CHUNKS)  // 2048
#define NSUMS 6
#define NITER (CHUNK / 4 / 256)  // 8

__global__ __launch_bounds__(256, 4) void loss_main(
    const float* __restrict__ pred, const int* __restrict__ label,
    float* __restrict__ ws, unsigned* __restrict__ counter,
    float* __restrict__ out, int fuse) {
  const int block = blockIdx.x;          // 0..2047
  const int plane = block >> 5;          // /K_CHUNKS
  const int chunk = block & (K_CHUNKS - 1);
  const long base = (long)plane * HW + (long)chunk * CHUNK;
  const f32x4* p4 = (const f32x4*)(pred + base);
  const i32x4* t4 = (const i32x4*)(label + base);
  const int tid = threadIdx.x;

  float s_pt = 0.f, s_pp = 0.f, s_p = 0.f;
  float nsum_t = 0.f;   // sum over ALL elems of  Bw * (-L)
  float nsum_1 = 0.f;   // sum over t==1 elems of Bw * (-L)
  int   s_ti = 0;       // integer count of positives

  // Issue ALL 16 loads (256 B/lane in flight), then fence the scheduler so
  // they cannot be sunk into the compute. Fully unrolled => static indexing.
  f32x4 P[NITER];
  i32x4 T[NITER];
#pragma unroll
  for (int it = 0; it < NITER; ++it) {
    P[it] = p4[tid + it * 256];
    T[it] = t4[tid + it * 256];
  }
  __builtin_amdgcn_sched_barrier(0);   // loads stay above; compute below

#pragma unroll
  for (int it = 0; it < NITER; ++it) {
#pragma unroll
    for (int j = 0; j < 4; ++j) {
      float pv = P[it][j];
      float tf = (float)T[it][j];                 // labels exactly 0/1
      float u   = __builtin_fmaf(tf, -2.0f, 1.0f);   // 1-2t
      float arg = __builtin_fmaf(pv, u, tf);         // t ? p : 1-p
      float x   = 1.0f - arg;                        // t ? 1-p : p
      float r   = __builtin_amdgcn_sqrtf(x);
      float Bw  = __builtin_amdgcn_exp2f(3.0f * r);  // 8^sqrt(x)
      float lg  = __builtin_amdgcn_logf(arg);        // log2
      float L   = fmaxf(0.69314718056f * lg, -100.0f);
      float c   = Bw * (-L);
      nsum_t += c;
      nsum_1  = __builtin_fmaf(tf, c, nsum_1);
      s_pt    = __builtin_fmaf(tf, pv, s_pt);
      s_pp    = __builtin_fmaf(pv, pv, s_pp);
      s_p    += pv;
      s_ti   += T[it][j];
    }
  }

  float s_t = (float)s_ti;

  // wave reduce (64 lanes), then cross-wave via LDS
  float vals[NSUMS] = {s_pt, s_pp, s_t, s_p, nsum_1, nsum_t};
  __shared__ float lds[4][NSUMS];
  __shared__ unsigned lflag;
#pragma unroll
  for (int q = 0; q < NSUMS; ++q) {
    float v = vals[q];
#pragma unroll
    for (int off = 32; off; off >>= 1) v += __shfl_down(v, off);
    vals[q] = v;
  }
  const int wave = tid >> 6;
  if ((tid & 63) == 0) {
#pragma unroll
    for (int q = 0; q < NSUMS; ++q) lds[wave][q] = vals[q];
  }
  __syncthreads();
  if (tid < NSUMS) {
    float v = lds[0][tid] + lds[1][tid] + lds[2][tid] + lds[3][tid];
    ws[block * NSUMS + tid] = v;
  }

  if (!fuse) return;

  // ---- last-block finalize (counter memset to 0 each call) ----
  __syncthreads();        // partial writes issued by whole block
  __threadfence();        // device-scope release
  if (tid == 0) {
    unsigned old = atomicAdd(counter, 1u);
    lflag = (old == (unsigned)(NBLOCKS - 1)) ? 1u : 0u;
  }
  __syncthreads();
  if (lflag == 0u) return;
  __threadfence();        // acquire: make all blocks' partials visible

  if (tid < 64) {
    const int p = tid;    // plane index; b = p>>2, c = p&3
    float s[NSUMS] = {0.f, 0.f, 0.f, 0.f, 0.f, 0.f};
    for (int k = 0; k < K_CHUNKS; ++k) {
      const float* w = ws + (p * K_CHUNKS + k) * NSUMS;
#pragma unroll
      for (int q = 0; q < NSUMS; ++q) s[q] += w[q];
    }
    const float s_pt2 = s[0], s_pp2 = s[1], s_t2 = s[2], s_p2 = s[3];
    const float sum1 = s[4];         // t==1 part
    const float sum2 = s[5] - s[4];  // t==0 part
    const float N = (float)HW;
    const float SM = 1e-6f;

    float dice = 1.0f - (2.0f * s_pt2 + SM) / (s_pp2 + s_t2 + SM);
    float inter2 = N - s_p2 - s_t2 + s_pt2;
    float denom2 = 2.0f * N - 2.0f * s_p2 + s_pp2 - s_t2;
    float rdice = 1.0f - (2.0f * inter2 + SM) / (denom2 + SM);

    float np4 = s_t2 + __shfl_xor(s_t2, 1);
    np4 += __shfl_xor(np4, 2);
    const float total = (float)(C_DIM * HW);  // 1048576
    float alpha = (total - np4) / total;

    float val = alpha * sum1 + (1.0f - alpha) * sum2
              + 2500.0f * (dice + rdice);

#pragma unroll
    for (int off = 32; off; off >>= 1) val += __shfl_down(val, off);
    if (p == 0) out[0] = val;
  }
}

// fallback second kernel (only used if ws lacks room for the counter)
__global__ __launch_bounds__(64) void loss_finalize(
    const float* __restrict__ ws, float* __restrict__ out) {
  const int p = threadIdx.x;
  float s[NSUMS] = {0.f, 0.f, 0.f, 0.f, 0.f, 0.f};
  for (int k = 0; k < K_CHUNKS; ++k) {
    const float* w = ws + (p * K_CHUNKS + k) * NSUMS;
#pragma unroll
    for (int q = 0; q < NSUMS; ++q) s[q] += w[q];
  }
  const float s_pt = s[0], s_pp = s[1], s_t = s[2], s_p = s[3];
  const float sum1 = s[4];
  const float sum2 = s[5] - s[4];
  const float N = (float)HW;
  const float SM = 1e-6f;
  float dice = 1.0f - (2.0f * s_pt + SM) / (s_pp + s_t + SM);
  float inter2 = N - s_p - s_t + s_pt;
  float denom2 = 2.0f * N - 2.0f * s_p + s_pp - s_t;
  float rdice = 1.0f - (2.0f * inter2 + SM) / (denom2 + SM);
  float np4 = s_t + __shfl_xor(s_t, 1);
  np4 += __shfl_xor(np4, 2);
  const float total = (float)(C_DIM * HW);
  float alpha = (total - np4) / total;
  float val = alpha * sum1 + (1.0f - alpha) * sum2 + 2500.0f * (dice + rdice);
#pragma unroll
  for (int off = 32; off; off >>= 1) val += __shfl_down(val, off);
  if (p == 0) out[0] = val;
}

extern "C" void kernel_launch(void* const* d_in, const int* in_sizes, int n_in,
                              void* d_out, int out_size, void* d_ws, size_t ws_size,
                              hipStream_t stream) {
  const float* pred = (const float*)d_in[0];
  const int* label = (const int*)d_in[1];
  float* out = (float*)d_out;
  float* ws = (float*)d_ws;  // partials: NBLOCKS*NSUMS*4 = 48 KiB (+4 counter)
  unsigned* counter = (unsigned*)((char*)d_ws + (size_t)NBLOCKS * NSUMS * 4);

  const int fuse = (ws_size >= (size_t)NBLOCKS * NSUMS * 4 + 4) ? 1 : 0;
  if (fuse) hipMemsetAsync(counter, 0, 4, stream);
  loss_main<<<NBLOCKS, 256, 0, stream>>>(pred, label, ws, counter, out, fuse);
  if (!fuse) loss_finalize<<<1, 64, 0, stream>>>(ws, out);
}

// Round 7
// 30.541 us; speedup vs baseline: 8.4830x; 8.4830x over previous
//
#include <hip/hip_runtime.h>

// ConvNeXtLoss: fused attention-BCE + dice + reverse-dice over (16,4,512,512).
// Pass 1: per-(b,c)-plane partial sums via global_load_lds staging.
// Pass 2: tiny 64-lane finalize kernel. NO fences/atomics anywhere.
//
// R7 changes vs R6 (259 us): R5==R6 despite different load code => the fused
// epilogue's per-block __threadfence (device-scope L2 writeback x2048) was
// the regression, NOT the loads. Dropped entirely -> two-kernel structure.
// Latency fix: stage each wave's whole chunk (8KB) via 8x
// __builtin_amdgcn_global_load_lds(16B/lane) -- no VGPR dest, compiler
// cannot sink them; ~128KB/CU in flight vs ~2KB/wave in R2. One
// __syncthreads() (m97 pattern) guarantees the vmcnt drain, then
// contiguous ds_read_b128 + the R2-validated branch-free math.

typedef float f32x4 __attribute__((ext_vector_type(4)));
typedef int   i32x4 __attribute__((ext_vector_type(4)));

#define B_DIM 16
#define C_DIM 4
#define HW 262144            // 512*512 plane
#define NPLANES 64           // B*C
#define K_CHUNKS 32          // blocks per plane
#define CHUNK (HW / K_CHUNKS)  // 8192 elements per block
#define NBLOCKS (NPLANES * K_CHUNKS)  // 2048
#define NSUMS 6
#define NTHREADS 512
#define NWAVES (NTHREADS / 64)   // 8
#define WELEMS (CHUNK / NWAVES)  // 1024 elems per wave
#define WOPS (WELEMS / 256)      // 4 DMA rounds per array (64 lanes x 4 f32)

__global__ __launch_bounds__(NTHREADS) void loss_main(
    const float* __restrict__ pred, const int* __restrict__ label,
    float* __restrict__ ws) {
  __shared__ float sp[NWAVES][WELEMS];   // 32 KB
  __shared__ int   st[NWAVES][WELEMS];   // 32 KB
  __shared__ float red[NWAVES][NSUMS];

  const int block = blockIdx.x;          // 0..2047
  const int plane = block >> 5;          // /K_CHUNKS
  const int chunk = block & (K_CHUNKS - 1);
  const int tid = threadIdx.x;
  const int w = tid >> 6, l = tid & 63;
  const long wbase = (long)plane * HW + (long)chunk * CHUNK + (long)w * WELEMS;
  const float* gp = pred + wbase;
  const int*   gt = label + wbase;

  // ---- stage the wave's entire chunk: 8 async DMA ops, 8 KB in flight ----
  // LDS dest is wave-uniform base + lane*16 (linear); global src is per-lane.
#pragma unroll
  for (int r = 0; r < WOPS; ++r) {
    __builtin_amdgcn_global_load_lds(
        (const __attribute__((address_space(1))) void*)(gp + r * 256 + l * 4),
        (__attribute__((address_space(3))) void*)(&sp[w][r * 256]), 16, 0, 0);
    __builtin_amdgcn_global_load_lds(
        (const __attribute__((address_space(1))) void*)(gt + r * 256 + l * 4),
        (__attribute__((address_space(3))) void*)(&st[w][r * 256]), 16, 0, 0);
  }
  __syncthreads();   // compiler-guaranteed vmcnt(0) drain (m97 pattern)

  float s_pt = 0.f, s_pp = 0.f, s_p = 0.f;
  float nsum_t = 0.f;   // sum over ALL elems of Bw * (-L)
  float nsum_1 = 0.f;   // sum over t==1 elems of Bw * (-L)
  int   s_ti = 0;       // integer count of positives

#pragma unroll
  for (int r = 0; r < WOPS; ++r) {
    f32x4 P = *(const f32x4*)&sp[w][r * 256 + l * 4];
    i32x4 T = *(const i32x4*)&st[w][r * 256 + l * 4];
#pragma unroll
    for (int j = 0; j < 4; ++j) {
      float pv = P[j];
      float tf = (float)T[j];                        // labels exactly 0/1
      float u   = __builtin_fmaf(tf, -2.0f, 1.0f);   // 1-2t
      float arg = __builtin_fmaf(pv, u, tf);         // t ? p : 1-p
      float x   = 1.0f - arg;                        // t ? 1-p : p
      float r_  = __builtin_amdgcn_sqrtf(x);
      float Bw  = __builtin_amdgcn_exp2f(3.0f * r_); // 8^sqrt(x)
      float lg  = __builtin_amdgcn_logf(arg);        // log2
      float L   = fmaxf(0.69314718056f * lg, -100.0f);
      float c   = Bw * (-L);
      nsum_t += c;
      nsum_1  = __builtin_fmaf(tf, c, nsum_1);
      s_pt    = __builtin_fmaf(tf, pv, s_pt);
      s_pp    = __builtin_fmaf(pv, pv, s_pp);
      s_p    += pv;
      s_ti   += T[j];
    }
  }

  float s_t = (float)s_ti;

  // wave reduce (64 lanes), then cross-wave via LDS
  float vals[NSUMS] = {s_pt, s_pp, s_t, s_p, nsum_1, nsum_t};
#pragma unroll
  for (int q = 0; q < NSUMS; ++q) {
    float v = vals[q];
#pragma unroll
    for (int off = 32; off; off >>= 1) v += __shfl_down(v, off);
    vals[q] = v;
  }
  if (l == 0) {
#pragma unroll
    for (int q = 0; q < NSUMS; ++q) red[w][q] = vals[q];
  }
  __syncthreads();
  if (tid < NSUMS) {
    float v = 0.f;
#pragma unroll
    for (int ww = 0; ww < NWAVES; ++ww) v += red[ww][tid];
    ws[block * NSUMS + tid] = v;
  }
}

__global__ __launch_bounds__(64) void loss_finalize(
    const float* __restrict__ ws, float* __restrict__ out) {
  const int p = threadIdx.x;  // plane index 0..63 ; b = p>>2, c = p&3
  float s[NSUMS] = {0.f, 0.f, 0.f, 0.f, 0.f, 0.f};
  for (int k = 0; k < K_CHUNKS; ++k) {
    const float* w = ws + (p * K_CHUNKS + k) * NSUMS;
#pragma unroll
    for (int q = 0; q < NSUMS; ++q) s[q] += w[q];
  }
  const float s_pt = s[0], s_pp = s[1], s_t = s[2], s_p = s[3];
  const float sum1 = s[4];             // t==1 part
  const float sum2 = s[5] - s[4];      // t==0 part
  const float N = (float)HW;
  const float SM = 1e-6f;

  // dice (per plane): 1 - (2*inter + S)/(sum p^2 + sum t + S)   [t^2 = t]
  float dice = 1.0f - (2.0f * s_pt + SM) / (s_pp + s_t + SM);
  // reverse dice via algebraic identities
  float inter2 = N - s_p - s_t + s_pt;
  float denom2 = 2.0f * N - 2.0f * s_p + s_pp - s_t;
  float rdice = 1.0f - (2.0f * inter2 + SM) / (denom2 + SM);

  // per-batch num_pos: sum s_t over the 4 channel lanes (p groups of 4)
  float np4 = s_t + __shfl_xor(s_t, 1);
  np4 += __shfl_xor(np4, 2);
  const float total = (float)(C_DIM * HW);  // 1048576
  float alpha = (total - np4) / total;

  float val = alpha * sum1 + (1.0f - alpha) * sum2
            + 2500.0f * (dice + rdice);   // DICE_COEFF == REV_DICE_COEFF

#pragma unroll
  for (int off = 32; off; off >>= 1) val += __shfl_down(val, off);
  if (p == 0) out[0] = val;
}

extern "C" void kernel_launch(void* const* d_in, const int* in_sizes, int n_in,
                              void* d_out, int out_size, void* d_ws, size_t ws_size,
                              hipStream_t stream) {
  const float* pred = (const float*)d_in[0];
  const int* label = (const int*)d_in[1];
  float* out = (float*)d_out;
  float* ws = (float*)d_ws;  // needs NBLOCKS*NSUMS*4 = 48 KiB

  loss_main<<<NBLOCKS, NTHREADS, 0, stream>>>(pred, label, ws);
  loss_finalize<<<1, 64, 0, stream>>>(ws, out);
}